// Round 1
// baseline (227.053 us; speedup 1.0000x reference)
//
#include <hip/hip_runtime.h>
#include <hip/hip_fp16.h>

// LatticeMultiHeadAttention — B=2, L=2048, D=1024, H=16, DK=64.
//
// Key simplification (exact, not approximate): the Kuramoto-phase bias is
// constant per head across (q,k). Softmax is shift-invariant, and masked
// entries are hard-set to -10000 whose exp underflows to exactly 0.0f in
// f32 regardless of bias (scores are O(1)). Hence bias/phases/neighbour
// tables have zero effect on the output -> skipped.
//
// Pipeline: QKV proj GEMMs (f16 MFMA, f32 accum) -> flash attention with
// key mask -> output proj GEMM (+bias). f16 chosen over bf16 for the
// 4x mantissa precision at identical MFMA rate.

#define B_ 2
#define L_ 2048
#define D_ 1024
#define H_ 16
#define DK_ 64

typedef _Float16 f16;
typedef _Float16 f16x4 __attribute__((ext_vector_type(4)));
typedef _Float16 f16x8 __attribute__((ext_vector_type(8)));
typedef float f32x4 __attribute__((ext_vector_type(4)));

// ---------------------------------------------------------------------------
// QKV projection: C[m,n] = sum_d X[m,d] * W[n,d]   (m=b*L+l, n=h*DK+k)
// stored as fp16 scattered to [b,h,l,k] for the attention kernel.
// Tile: BM=128, BN=128, BK=32; 4 waves, each 64x64; mfma_f32_16x16x32_f16.
// ---------------------------------------------------------------------------
__global__ __launch_bounds__(256) void qkv_proj_kernel(
    const float* __restrict__ query, const float* __restrict__ keyx,
    const float* __restrict__ value,
    const float* __restrict__ Wq, const float* __restrict__ Wk,
    const float* __restrict__ Wv,
    f16* __restrict__ Qh, f16* __restrict__ Kh, f16* __restrict__ Vh)
{
    const int z = blockIdx.z;
    const float* X = (z == 0) ? query : (z == 1) ? keyx : value;
    const float* W = (z == 0) ? Wq : (z == 1) ? Wk : Wv;
    f16* out = (z == 0) ? Qh : (z == 1) ? Kh : Vh;

    const int m0 = blockIdx.x * 128;
    const int n0 = blockIdx.y * 128;
    const int tid = threadIdx.x;
    const int lane = tid & 63;
    const int w = tid >> 6;
    const int wr = (w >> 1) * 64, wc = (w & 1) * 64;

    // +8 half padding per row -> row stride 40 halves (80B), kills the
    // power-of-2 bank pattern on ds_read_b128 (2-way residual = free).
    __shared__ f16 As[128 * 40];
    __shared__ f16 Ws[128 * 40];

    f32x4 acc[4][4] = {};

    for (int kk = 0; kk < D_; kk += 32) {
        __syncthreads();
        {
            int r = tid >> 3;          // 0..31
            int c = (tid & 7) * 4;     // 0..28
            #pragma unroll
            for (int p = 0; p < 4; ++p) {
                int row = p * 32 + r;
                float4 va = *(const float4*)&X[(size_t)(m0 + row) * D_ + kk + c];
                f16x4 ha = { (f16)va.x, (f16)va.y, (f16)va.z, (f16)va.w };
                *(f16x4*)&As[row * 40 + c] = ha;
                float4 vb = *(const float4*)&W[(size_t)(n0 + row) * D_ + kk + c];
                f16x4 hb = { (f16)vb.x, (f16)vb.y, (f16)vb.z, (f16)vb.w };
                *(f16x4*)&Ws[row * 40 + c] = hb;
            }
        }
        __syncthreads();

        f16x8 af[4], bf[4];
        const int lg = (lane >> 4) * 8;
        #pragma unroll
        for (int i = 0; i < 4; ++i) {
            af[i] = *(const f16x8*)&As[(wr + i * 16 + (lane & 15)) * 40 + lg];
            bf[i] = *(const f16x8*)&Ws[(wc + i * 16 + (lane & 15)) * 40 + lg];
        }
        #pragma unroll
        for (int i = 0; i < 4; ++i)
            #pragma unroll
            for (int j = 0; j < 4; ++j)
                acc[i][j] = __builtin_amdgcn_mfma_f32_16x16x32_f16(af[i], bf[j], acc[i][j], 0, 0, 0);
    }

    // C/D layout (verified on gfx950): col = lane&15, row = (lane>>4)*4 + reg
    #pragma unroll
    for (int i = 0; i < 4; ++i) {
        int grow = m0 + wr + i * 16 + (lane >> 4) * 4;
        #pragma unroll
        for (int j = 0; j < 4; ++j) {
            int gcol = n0 + wc + j * 16 + (lane & 15);
            int h = gcol >> 6, k = gcol & 63;
            #pragma unroll
            for (int r = 0; r < 4; ++r) {
                int row = grow + r;
                int b = row >> 11, l = row & (L_ - 1);
                out[(((size_t)(b * H_ + h)) * L_ + l) * DK_ + k] = (f16)acc[i][j][r];
            }
        }
    }
}

// ---------------------------------------------------------------------------
// Flash attention. Block = 4 waves, 64 q rows (16/wave). Key tiles of 64.
// K staged row-major in LDS; V staged TRANSPOSED (dv-major) so the PV
// B-operand is a contiguous f16x8 read. P goes through a padded LDS tile
// to convert the QK^T D-layout into the PV A-layout.
// ---------------------------------------------------------------------------
__global__ __launch_bounds__(256) void attn_kernel(
    const f16* __restrict__ Qh, const f16* __restrict__ Kh,
    const f16* __restrict__ Vh, const int* __restrict__ mask,
    f16* __restrict__ Oh)
{
    const int bh = blockIdx.y;          // b*H + h
    const int b = bh >> 4, h = bh & 15;
    const int q0 = blockIdx.x * 64;
    const int tid = threadIdx.x;
    const int lane = tid & 63;
    const int w = tid >> 6;

    __shared__ f16 Ks[64 * 72];
    __shared__ f16 Vt[64 * 72];
    __shared__ float moff[64];
    __shared__ f16 Plds[4][16 * 72];

    const size_t base = (size_t)bh * L_ * DK_;

    // Q fragments for this wave's 16 q rows, held in registers all kernel.
    f16x8 qf[2];
    {
        int qrow = q0 + w * 16 + (lane & 15);
        const f16* qptr = Qh + base + (size_t)qrow * DK_ + (lane >> 4) * 8;
        qf[0] = *(const f16x8*)(qptr);
        qf[1] = *(const f16x8*)(qptr + 32);
    }

    f32x4 acc[4] = {};            // acc[f][reg]: dv=f*16+(lane&15), q=(lane>>4)*4+reg
    float mrun[4], lrun[4];
    #pragma unroll
    for (int r = 0; r < 4; ++r) { mrun[r] = -1e30f; lrun[r] = 0.f; }

    for (int k0 = 0; k0 < L_; k0 += 64) {
        __syncthreads();   // protect Ks/Vt against previous iteration's readers
        {
            int r = tid >> 2;             // key row 0..63
            int c = (tid & 3) * 16;       // 0,16,32,48
            const f16* kp = Kh + base + (size_t)(k0 + r) * DK_ + c;
            f16x8 k0v = *(const f16x8*)kp;
            f16x8 k1v = *(const f16x8*)(kp + 8);
            *(f16x8*)&Ks[r * 72 + c] = k0v;
            *(f16x8*)&Ks[r * 72 + c + 8] = k1v;
            const f16* vp = Vh + base + (size_t)(k0 + r) * DK_ + c;
            f16x8 v0v = *(const f16x8*)vp;
            f16x8 v1v = *(const f16x8*)(vp + 8);
            #pragma unroll
            for (int j = 0; j < 8; ++j) {
                Vt[(c + j) * 72 + r]     = v0v[j];
                Vt[(c + 8 + j) * 72 + r] = v1v[j];
            }
            if (tid < 64) moff[tid] = mask[b * L_ + k0 + tid] ? 0.f : -10000.f;
        }
        __syncthreads();

        // ---- QK^T: 4 subtiles of 16 keys; D layout: key=lane&15, q=(lane>>4)*4+reg
        f32x4 sv[4];
        #pragma unroll
        for (int kt = 0; kt < 4; ++kt) {
            f32x4 s = {};
            const f16* krow = &Ks[(kt * 16 + (lane & 15)) * 72 + (lane >> 4) * 8];
            s = __builtin_amdgcn_mfma_f32_16x16x32_f16(qf[0], *(const f16x8*)krow, s, 0, 0, 0);
            s = __builtin_amdgcn_mfma_f32_16x16x32_f16(qf[1], *(const f16x8*)(krow + 32), s, 0, 0, 0);
            float mo = moff[kt * 16 + (lane & 15)];
            #pragma unroll
            for (int r = 0; r < 4; ++r) sv[kt][r] = s[r] * 0.125f + mo;
        }

        // ---- online softmax (row = fixed reg across the 16 lanes of a group)
        float scl[4];
        #pragma unroll
        for (int r = 0; r < 4; ++r) {
            float m = fmaxf(fmaxf(sv[0][r], sv[1][r]), fmaxf(sv[2][r], sv[3][r]));
            m = fmaxf(m, __shfl_xor(m, 1, 64));
            m = fmaxf(m, __shfl_xor(m, 2, 64));
            m = fmaxf(m, __shfl_xor(m, 4, 64));
            m = fmaxf(m, __shfl_xor(m, 8, 64));
            float mn = fmaxf(mrun[r], m);
            scl[r] = __expf(mrun[r] - mn);
            mrun[r] = mn;
        }
        float ls[4] = {0.f, 0.f, 0.f, 0.f};
        #pragma unroll
        for (int kt = 0; kt < 4; ++kt)
            #pragma unroll
            for (int r = 0; r < 4; ++r) {
                float p = __expf(sv[kt][r] - mrun[r]);
                sv[kt][r] = p;
                ls[r] += p;
            }
        #pragma unroll
        for (int r = 0; r < 4; ++r) {
            float s = ls[r];
            s += __shfl_xor(s, 1, 64);
            s += __shfl_xor(s, 2, 64);
            s += __shfl_xor(s, 4, 64);
            s += __shfl_xor(s, 8, 64);
            lrun[r] = lrun[r] * scl[r] + s;
            acc[0][r] *= scl[r]; acc[1][r] *= scl[r];
            acc[2][r] *= scl[r]; acc[3][r] *= scl[r];
        }

        // ---- P (D-layout) -> LDS -> A-layout fragments for PV
        f16* pl = Plds[w];
        #pragma unroll
        for (int kt = 0; kt < 4; ++kt) {
            int key = kt * 16 + (lane & 15);
            #pragma unroll
            for (int r = 0; r < 4; ++r)
                pl[((lane >> 4) * 4 + r) * 72 + key] = (f16)sv[kt][r];
        }
        asm volatile("s_waitcnt lgkmcnt(0)" ::: "memory");  // intra-wave RAW on LDS

        #pragma unroll
        for (int kc = 0; kc < 2; ++kc) {
            f16x8 pa = *(const f16x8*)&pl[(lane & 15) * 72 + kc * 32 + (lane >> 4) * 8];
            #pragma unroll
            for (int f = 0; f < 4; ++f) {
                f16x8 vb = *(const f16x8*)&Vt[(f * 16 + (lane & 15)) * 72 + kc * 32 + (lane >> 4) * 8];
                acc[f] = __builtin_amdgcn_mfma_f32_16x16x32_f16(pa, vb, acc[f], 0, 0, 0);
            }
        }
    }

    // epilogue: normalize and store fp16 to Oh[b, l, h*64+dv]
    #pragma unroll
    for (int r = 0; r < 4; ++r) {
        float inv = 1.f / lrun[r];
        int q = q0 + w * 16 + (lane >> 4) * 4 + r;
        #pragma unroll
        for (int f = 0; f < 4; ++f) {
            int dv = f * 16 + (lane & 15);
            Oh[((size_t)(b * L_ + q)) * D_ + h * 64 + dv] = (f16)(acc[f][r] * inv);
        }
    }
}

// ---------------------------------------------------------------------------
// Output projection: Y[m,j] = sum_n Oh[m,n] * out_w[j,n] + out_b[j], f32 out.
// ---------------------------------------------------------------------------
__global__ __launch_bounds__(256) void out_proj_kernel(
    const f16* __restrict__ Oh, const float* __restrict__ outw,
    const float* __restrict__ outb, float* __restrict__ Y)
{
    const int m0 = blockIdx.x * 128;
    const int n0 = blockIdx.y * 128;
    const int tid = threadIdx.x;
    const int lane = tid & 63;
    const int w = tid >> 6;
    const int wr = (w >> 1) * 64, wc = (w & 1) * 64;

    __shared__ f16 As[128 * 40];
    __shared__ f16 Ws[128 * 40];

    f32x4 acc[4][4] = {};

    for (int kk = 0; kk < D_; kk += 32) {
        __syncthreads();
        {
            int r = tid >> 3;
            int c = (tid & 7) * 4;
            #pragma unroll
            for (int p = 0; p < 4; ++p) {
                int row = p * 32 + r;
                f16x4 ha = *(const f16x4*)&Oh[(size_t)(m0 + row) * D_ + kk + c];
                *(f16x4*)&As[row * 40 + c] = ha;
                float4 vb = *(const float4*)&outw[(size_t)(n0 + row) * D_ + kk + c];
                f16x4 hb = { (f16)vb.x, (f16)vb.y, (f16)vb.z, (f16)vb.w };
                *(f16x4*)&Ws[row * 40 + c] = hb;
            }
        }
        __syncthreads();

        f16x8 af[4], bf[4];
        const int lg = (lane >> 4) * 8;
        #pragma unroll
        for (int i = 0; i < 4; ++i) {
            af[i] = *(const f16x8*)&As[(wr + i * 16 + (lane & 15)) * 40 + lg];
            bf[i] = *(const f16x8*)&Ws[(wc + i * 16 + (lane & 15)) * 40 + lg];
        }
        #pragma unroll
        for (int i = 0; i < 4; ++i)
            #pragma unroll
            for (int j = 0; j < 4; ++j)
                acc[i][j] = __builtin_amdgcn_mfma_f32_16x16x32_f16(af[i], bf[j], acc[i][j], 0, 0, 0);
    }

    #pragma unroll
    for (int i = 0; i < 4; ++i) {
        int grow = m0 + wr + i * 16 + (lane >> 4) * 4;
        #pragma unroll
        for (int j = 0; j < 4; ++j) {
            int gcol = n0 + wc + j * 16 + (lane & 15);
            float bias = outb[gcol];
            #pragma unroll
            for (int r = 0; r < 4; ++r)
                Y[(size_t)(grow + r) * D_ + gcol] = acc[i][j][r] + bias;
        }
    }
}

extern "C" void kernel_launch(void* const* d_in, const int* in_sizes, int n_in,
                              void* d_out, int out_size, void* d_ws, size_t ws_size,
                              hipStream_t stream) {
    const float* query = (const float*)d_in[0];
    const float* key   = (const float*)d_in[1];
    const float* value = (const float*)d_in[2];
    const float* Wq    = (const float*)d_in[3];
    const float* Wk    = (const float*)d_in[4];
    const float* Wv    = (const float*)d_in[5];
    // d_in[6] coupling_strength, d_in[9] neighbour_w, d_in[11] neighbour_idx:
    // unused — head bias cancels in softmax exactly (see header comment).
    const float* outw  = (const float*)d_in[7];
    const float* outb  = (const float*)d_in[8];
    const int*   mask  = (const int*)d_in[10];
    float* Y = (float*)d_out;

    char* ws = (char*)d_ws;
    f16* Qh = (f16*)(ws);                 //  8 MiB: [b,h,l,k] fp16
    f16* Kh = (f16*)(ws + 8388608);       //  8 MiB
    f16* Vh = (f16*)(ws + 16777216);      //  8 MiB
    f16* Oh = (f16*)(ws + 25165824);      //  8 MiB: [b,l,h*64+k] fp16

    qkv_proj_kernel<<<dim3(32, 8, 3), 256, 0, stream>>>(query, key, value,
                                                        Wq, Wk, Wv, Qh, Kh, Vh);
    attn_kernel<<<dim3(32, 32), 256, 0, stream>>>(Qh, Kh, Vh, mask, Oh);
    out_proj_kernel<<<dim3(32, 8), 256, 0, stream>>>(Oh, outw, outb, Y);
}

// Round 2
// 186.500 us; speedup vs baseline: 1.2174x; 1.2174x over previous
//
#include <hip/hip_runtime.h>
#include <hip/hip_fp16.h>

// LatticeMultiHeadAttention — B=2, L=2048, D=1024, H=16, DK=64.
//
// Phase/bias computation skipped (exact): per-head constant bias cancels in
// softmax; masked scores (-10000) underflow to 0 regardless of bias.
//
// Round 2: attn restructured — swapped QK^T (S^T layout -> per-lane scalar
// softmax, vectorized P store), O^T PV orientation, conflict-free V
// transpose staging, reg-prefetch software pipeline, exp2-domain softmax
// (scale folded into Q at projection), setprio around MFMA.

#define B_ 2
#define L_ 2048
#define D_ 1024
#define H_ 16
#define DK_ 64

// 0.125 * log2(e): QK^T scale folded into Q projection, softmax in exp2 domain.
#define QSCALE 0.1803368801111244f
#define MASKOFF -14427.0f

typedef _Float16 f16;
typedef _Float16 f16x4 __attribute__((ext_vector_type(4)));
typedef _Float16 f16x8 __attribute__((ext_vector_type(8)));
typedef float f32x4 __attribute__((ext_vector_type(4)));

// ---------------------------------------------------------------------------
// QKV projection GEMM (f32 in, f16 out scattered to [b,h,l,k]).
// ---------------------------------------------------------------------------
__global__ __launch_bounds__(256) void qkv_proj_kernel(
    const float* __restrict__ query, const float* __restrict__ keyx,
    const float* __restrict__ value,
    const float* __restrict__ Wq, const float* __restrict__ Wk,
    const float* __restrict__ Wv,
    f16* __restrict__ Qh, f16* __restrict__ Kh, f16* __restrict__ Vh)
{
    const int z = blockIdx.z;
    const float* X = (z == 0) ? query : (z == 1) ? keyx : value;
    const float* W = (z == 0) ? Wq : (z == 1) ? Wk : Wv;
    f16* out = (z == 0) ? Qh : (z == 1) ? Kh : Vh;
    const float qs = (z == 0) ? QSCALE : 1.0f;

    const int m0 = blockIdx.x * 128;
    const int n0 = blockIdx.y * 128;
    const int tid = threadIdx.x;
    const int lane = tid & 63;
    const int w = tid >> 6;
    const int wr = (w >> 1) * 64, wc = (w & 1) * 64;

    __shared__ f16 As[128 * 40];
    __shared__ f16 Ws[128 * 40];

    f32x4 acc[4][4] = {};

    for (int kk = 0; kk < D_; kk += 32) {
        __syncthreads();
        {
            int r = tid >> 3;
            int c = (tid & 7) * 4;
            #pragma unroll
            for (int p = 0; p < 4; ++p) {
                int row = p * 32 + r;
                float4 va = *(const float4*)&X[(size_t)(m0 + row) * D_ + kk + c];
                f16x4 ha = { (f16)(va.x * qs), (f16)(va.y * qs), (f16)(va.z * qs), (f16)(va.w * qs) };
                *(f16x4*)&As[row * 40 + c] = ha;
                float4 vb = *(const float4*)&W[(size_t)(n0 + row) * D_ + kk + c];
                f16x4 hb = { (f16)vb.x, (f16)vb.y, (f16)vb.z, (f16)vb.w };
                *(f16x4*)&Ws[row * 40 + c] = hb;
            }
        }
        __syncthreads();

        f16x8 af[4], bf[4];
        const int lg = (lane >> 4) * 8;
        #pragma unroll
        for (int i = 0; i < 4; ++i) {
            af[i] = *(const f16x8*)&As[(wr + i * 16 + (lane & 15)) * 40 + lg];
            bf[i] = *(const f16x8*)&Ws[(wc + i * 16 + (lane & 15)) * 40 + lg];
        }
        #pragma unroll
        for (int i = 0; i < 4; ++i)
            #pragma unroll
            for (int j = 0; j < 4; ++j)
                acc[i][j] = __builtin_amdgcn_mfma_f32_16x16x32_f16(af[i], bf[j], acc[i][j], 0, 0, 0);
    }

    #pragma unroll
    for (int i = 0; i < 4; ++i) {
        int grow = m0 + wr + i * 16 + (lane >> 4) * 4;
        #pragma unroll
        for (int j = 0; j < 4; ++j) {
            int gcol = n0 + wc + j * 16 + (lane & 15);
            int h = gcol >> 6, k = gcol & 63;
            #pragma unroll
            for (int r = 0; r < 4; ++r) {
                int row = grow + r;
                int b = row >> 11, l = row & (L_ - 1);
                out[(((size_t)(b * H_ + h)) * L_ + l) * DK_ + k] = (f16)acc[i][j][r];
            }
        }
    }
}

// ---------------------------------------------------------------------------
// Flash attention, swapped-operand form. Block = 4 waves, 64 q rows.
// S^T = mfma(K, Q): lane holds q = lane&15, 16 keys in regs -> scalar
// per-lane softmax. PV computes O^T = mfma(V^T, P^T): col stays q = lane&15.
// Reg-prefetch pipeline over 64-key tiles.
// ---------------------------------------------------------------------------
__global__ __launch_bounds__(256) void attn_kernel(
    const f16* __restrict__ Qh, const f16* __restrict__ Kh,
    const f16* __restrict__ Vh, const int* __restrict__ mask,
    f16* __restrict__ Oh)
{
    const int bh = blockIdx.y;
    const int b = bh >> 4, h = bh & 15;
    const int q0 = blockIdx.x * 64;
    const int tid = threadIdx.x;
    const int lane = tid & 63;
    const int w = tid >> 6;

    __shared__ f16 Ks[64 * 72];
    __shared__ f16 Vt[64 * 72];
    __shared__ f16 Plds[4][16 * 72];
    __shared__ float moff[64];

    const size_t base = (size_t)bh * L_ * DK_;
    const int* maskp = mask + b * L_;

    // Q fragment (B-operand): q = q0 + w*16 + (lane&15), d = (lane>>4)*8 + j
    f16x8 qf[2];
    {
        int qrow = q0 + w * 16 + (lane & 15);
        const f16* qptr = Qh + base + (size_t)qrow * DK_ + (lane >> 4) * 8;
        qf[0] = *(const f16x8*)(qptr);
        qf[1] = *(const f16x8*)(qptr + 32);
    }

    // staging maps
    const int krow = tid >> 2, kcol = (tid & 3) * 16;   // K: coalesced loads, b128 stores
    const int vkey = tid & 63, vdv = (tid >> 6) * 16;   // V: conflict-free transpose stores

    f32x4 acc[4] = {};   // O^T: dv = f*16 + (lane>>4)*4 + reg, q = lane&15
    float mrun = -1e30f, lrun = 0.f;

    f16x8 kA0, kA1, vA0, vA1; int mA;
    f16x8 kB0, kB1, vB0, vB1; int mB;

    auto issue = [&](int k0, f16x8& k0r, f16x8& k1r, f16x8& v0r, f16x8& v1r, int& mv) {
        const f16* kp = Kh + base + (size_t)(k0 + krow) * DK_ + kcol;
        k0r = *(const f16x8*)kp;
        k1r = *(const f16x8*)(kp + 8);
        const f16* vp = Vh + base + (size_t)(k0 + vkey) * DK_ + vdv;
        v0r = *(const f16x8*)vp;
        v1r = *(const f16x8*)(vp + 8);
        mv = maskp[k0 + (tid & 63)];
    };

    auto store_tile = [&](const f16x8& k0r, const f16x8& k1r,
                          const f16x8& v0r, const f16x8& v1r, int mv) {
        *(f16x8*)&Ks[krow * 72 + kcol] = k0r;
        *(f16x8*)&Ks[krow * 72 + kcol + 8] = k1r;
        #pragma unroll
        for (int j = 0; j < 8; ++j) {
            Vt[(vdv + j) * 72 + vkey] = v0r[j];
            Vt[(vdv + 8 + j) * 72 + vkey] = v1r[j];
        }
        if (tid < 64) moff[tid] = mv ? 0.f : MASKOFF;
    };

    auto compute = [&]() {
        float sv[16];
        __builtin_amdgcn_s_setprio(1);
        #pragma unroll
        for (int kt = 0; kt < 4; ++kt) {
            f32x4 s = {};
            const f16* ka = &Ks[(kt * 16 + (lane & 15)) * 72 + (lane >> 4) * 8];
            s = __builtin_amdgcn_mfma_f32_16x16x32_f16(*(const f16x8*)ka, qf[0], s, 0, 0, 0);
            s = __builtin_amdgcn_mfma_f32_16x16x32_f16(*(const f16x8*)(ka + 32), qf[1], s, 0, 0, 0);
            float4 mo = *(const float4*)&moff[kt * 16 + (lane >> 4) * 4];
            sv[kt * 4 + 0] = s[0] + mo.x;
            sv[kt * 4 + 1] = s[1] + mo.y;
            sv[kt * 4 + 2] = s[2] + mo.z;
            sv[kt * 4 + 3] = s[3] + mo.w;
        }
        __builtin_amdgcn_s_setprio(0);

        // scalar online softmax in exp2 domain (row = this lane's q)
        float t0 = fmaxf(fmaxf(sv[0], sv[1]), fmaxf(sv[2], sv[3]));
        float t1 = fmaxf(fmaxf(sv[4], sv[5]), fmaxf(sv[6], sv[7]));
        float t2 = fmaxf(fmaxf(sv[8], sv[9]), fmaxf(sv[10], sv[11]));
        float t3 = fmaxf(fmaxf(sv[12], sv[13]), fmaxf(sv[14], sv[15]));
        float m = fmaxf(fmaxf(t0, t1), fmaxf(t2, t3));
        m = fmaxf(m, __shfl_xor(m, 16, 64));
        m = fmaxf(m, __shfl_xor(m, 32, 64));
        float mn = fmaxf(mrun, m);
        float scl = exp2f(mrun - mn);
        mrun = mn;

        float ls0 = 0.f, ls1 = 0.f, ls2 = 0.f, ls3 = 0.f;
        #pragma unroll
        for (int i = 0; i < 4; ++i) {
            float p0 = exp2f(sv[i * 4 + 0] - mn);
            float p1 = exp2f(sv[i * 4 + 1] - mn);
            float p2 = exp2f(sv[i * 4 + 2] - mn);
            float p3 = exp2f(sv[i * 4 + 3] - mn);
            sv[i * 4 + 0] = p0; sv[i * 4 + 1] = p1;
            sv[i * 4 + 2] = p2; sv[i * 4 + 3] = p3;
            ls0 += p0; ls1 += p1; ls2 += p2; ls3 += p3;
        }
        float ls = (ls0 + ls1) + (ls2 + ls3);
        ls += __shfl_xor(ls, 16, 64);
        ls += __shfl_xor(ls, 32, 64);
        lrun = lrun * scl + ls;
        #pragma unroll
        for (int f = 0; f < 4; ++f) acc[f] *= scl;

        // P^T -> LDS, vectorized: lane owns row q = lane&15, writes 4
        // consecutive keys per subtile (key = kt*16 + (lane>>4)*4 + r).
        f16* pl = (f16*)Plds[w];
        #pragma unroll
        for (int kt = 0; kt < 4; ++kt) {
            f16x4 pk = { (f16)sv[kt * 4 + 0], (f16)sv[kt * 4 + 1],
                         (f16)sv[kt * 4 + 2], (f16)sv[kt * 4 + 3] };
            *(f16x4*)&pl[(lane & 15) * 72 + kt * 16 + (lane >> 4) * 4] = pk;
        }
        asm volatile("s_waitcnt lgkmcnt(0)" ::: "memory");

        // PV: O^T = V^T * P^T.  A = Vt rows (dv), B = P^T cols (q = lane&15).
        __builtin_amdgcn_s_setprio(1);
        #pragma unroll
        for (int kc = 0; kc < 2; ++kc) {
            f16x8 pb = *(const f16x8*)&pl[(lane & 15) * 72 + kc * 32 + (lane >> 4) * 8];
            #pragma unroll
            for (int f = 0; f < 4; ++f) {
                f16x8 va = *(const f16x8*)&Vt[(f * 16 + (lane & 15)) * 72 + kc * 32 + (lane >> 4) * 8];
                acc[f] = __builtin_amdgcn_mfma_f32_16x16x32_f16(va, pb, acc[f], 0, 0, 0);
            }
        }
        __builtin_amdgcn_s_setprio(0);
    };

    issue(0, kA0, kA1, vA0, vA1, mA);
    for (int k0 = 0; k0 < L_; k0 += 128) {
        __syncthreads();
        store_tile(kA0, kA1, vA0, vA1, mA);
        issue(k0 + 64, kB0, kB1, vB0, vB1, mB);
        __syncthreads();
        compute();

        __syncthreads();
        store_tile(kB0, kB1, vB0, vB1, mB);
        if (k0 + 128 < L_) issue(k0 + 128, kA0, kA1, vA0, vA1, mA);
        __syncthreads();
        compute();
    }

    // epilogue: normalize (per-lane scalar l) and store O[q][dv] as f16x4
    float inv = 1.f / lrun;
    int q = q0 + w * 16 + (lane & 15);
    #pragma unroll
    for (int f = 0; f < 4; ++f) {
        f16x4 o = { (f16)(acc[f][0] * inv), (f16)(acc[f][1] * inv),
                    (f16)(acc[f][2] * inv), (f16)(acc[f][3] * inv) };
        *(f16x4*)&Oh[((size_t)(b * L_ + q)) * D_ + h * 64 + f * 16 + (lane >> 4) * 4] = o;
    }
}

// ---------------------------------------------------------------------------
// Output projection GEMM (+bias), f32 out.
// ---------------------------------------------------------------------------
__global__ __launch_bounds__(256) void out_proj_kernel(
    const f16* __restrict__ Oh, const float* __restrict__ outw,
    const float* __restrict__ outb, float* __restrict__ Y)
{
    const int m0 = blockIdx.x * 128;
    const int n0 = blockIdx.y * 128;
    const int tid = threadIdx.x;
    const int lane = tid & 63;
    const int w = tid >> 6;
    const int wr = (w >> 1) * 64, wc = (w & 1) * 64;

    __shared__ f16 As[128 * 40];
    __shared__ f16 Ws[128 * 40];

    f32x4 acc[4][4] = {};

    for (int kk = 0; kk < D_; kk += 32) {
        __syncthreads();
        {
            int r = tid >> 3;
            int c = (tid & 7) * 4;
            #pragma unroll
            for (int p = 0; p < 4; ++p) {
                int row = p * 32 + r;
                f16x4 ha = *(const f16x4*)&Oh[(size_t)(m0 + row) * D_ + kk + c];
                *(f16x4*)&As[row * 40 + c] = ha;
                float4 vb = *(const float4*)&outw[(size_t)(n0 + row) * D_ + kk + c];
                f16x4 hb = { (f16)vb.x, (f16)vb.y, (f16)vb.z, (f16)vb.w };
                *(f16x4*)&Ws[row * 40 + c] = hb;
            }
        }
        __syncthreads();

        f16x8 af[4], bf[4];
        const int lg = (lane >> 4) * 8;
        #pragma unroll
        for (int i = 0; i < 4; ++i) {
            af[i] = *(const f16x8*)&As[(wr + i * 16 + (lane & 15)) * 40 + lg];
            bf[i] = *(const f16x8*)&Ws[(wc + i * 16 + (lane & 15)) * 40 + lg];
        }
        #pragma unroll
        for (int i = 0; i < 4; ++i)
            #pragma unroll
            for (int j = 0; j < 4; ++j)
                acc[i][j] = __builtin_amdgcn_mfma_f32_16x16x32_f16(af[i], bf[j], acc[i][j], 0, 0, 0);
    }

    #pragma unroll
    for (int i = 0; i < 4; ++i) {
        int grow = m0 + wr + i * 16 + (lane >> 4) * 4;
        #pragma unroll
        for (int j = 0; j < 4; ++j) {
            int gcol = n0 + wc + j * 16 + (lane & 15);
            float bias = outb[gcol];
            #pragma unroll
            for (int r = 0; r < 4; ++r)
                Y[(size_t)(grow + r) * D_ + gcol] = acc[i][j][r] + bias;
        }
    }
}

extern "C" void kernel_launch(void* const* d_in, const int* in_sizes, int n_in,
                              void* d_out, int out_size, void* d_ws, size_t ws_size,
                              hipStream_t stream) {
    const float* query = (const float*)d_in[0];
    const float* key   = (const float*)d_in[1];
    const float* value = (const float*)d_in[2];
    const float* Wq    = (const float*)d_in[3];
    const float* Wk    = (const float*)d_in[4];
    const float* Wv    = (const float*)d_in[5];
    const float* outw  = (const float*)d_in[7];
    const float* outb  = (const float*)d_in[8];
    const int*   mask  = (const int*)d_in[10];
    float* Y = (float*)d_out;

    char* ws = (char*)d_ws;
    f16* Qh = (f16*)(ws);                 //  8 MiB: [b,h,l,k] f16 (pre-scaled)
    f16* Kh = (f16*)(ws + 8388608);       //  8 MiB
    f16* Vh = (f16*)(ws + 16777216);      //  8 MiB
    f16* Oh = (f16*)(ws + 25165824);      //  8 MiB: [b,l,h*64+k] f16

    qkv_proj_kernel<<<dim3(32, 8, 3), 256, 0, stream>>>(query, key, value,
                                                        Wq, Wk, Wv, Qh, Kh, Vh);
    attn_kernel<<<dim3(32, 32), 256, 0, stream>>>(Qh, Kh, Vh, mask, Oh);
    out_proj_kernel<<<dim3(32, 8), 256, 0, stream>>>(Oh, outw, outb, Y);
}

// Round 4
// 185.246 us; speedup vs baseline: 1.2257x; 1.0068x over previous
//
#include <hip/hip_runtime.h>
#include <hip/hip_fp16.h>

// LatticeMultiHeadAttention — B=2, L=2048, D=1024, H=16, DK=64.
//
// Phase/bias computation skipped (exact): per-head constant bias cancels in
// softmax; masked scores (-10000) underflow to 0 regardless of bias.
//
// Round 4 = round 3 with the cvt_pkrtz return-type fix (bit_cast from
// __fp16 vector). V pre-transposed at projection; attn stages V^T with pure
// b128 copies; mask offsets hoisted to LDS once, folded into MFMA C-input;
// exact defer-max; XCD-aware block swizzle.

#define B_ 2
#define L_ 2048
#define D_ 1024
#define H_ 16
#define DK_ 64

// 0.125 * log2(e): QK^T scale folded into Q projection, softmax in exp2 domain.
#define QSCALE 0.1803368801111244f
#define MASKOFF -14427.0f

typedef _Float16 f16;
typedef _Float16 f16x2 __attribute__((ext_vector_type(2)));
typedef _Float16 f16x4 __attribute__((ext_vector_type(4)));
typedef _Float16 f16x8 __attribute__((ext_vector_type(8)));
typedef __fp16 hf16x2 __attribute__((ext_vector_type(2)));
typedef float f32x4 __attribute__((ext_vector_type(4)));

// ---------------------------------------------------------------------------
// QKV projection GEMM (f32 in, f16 out). Q,K scattered to [b,h,l,k];
// V written TRANSPOSED to [b,h,k,l] (vectorized f16x4 stores) so the attn
// kernel can stage V^T with plain row-major b128 copies.
// ---------------------------------------------------------------------------
__global__ __launch_bounds__(256) void qkv_proj_kernel(
    const float* __restrict__ query, const float* __restrict__ keyx,
    const float* __restrict__ value,
    const float* __restrict__ Wq, const float* __restrict__ Wk,
    const float* __restrict__ Wv,
    f16* __restrict__ Qh, f16* __restrict__ Kh, f16* __restrict__ VhT)
{
    const int z = blockIdx.z;
    const float* X = (z == 0) ? query : (z == 1) ? keyx : value;
    const float* W = (z == 0) ? Wq : (z == 1) ? Wk : Wv;
    f16* out = (z == 0) ? Qh : (z == 1) ? Kh : VhT;
    const float qs = (z == 0) ? QSCALE : 1.0f;

    const int m0 = blockIdx.x * 128;
    const int n0 = blockIdx.y * 128;
    const int tid = threadIdx.x;
    const int lane = tid & 63;
    const int w = tid >> 6;
    const int wr = (w >> 1) * 64, wc = (w & 1) * 64;

    __shared__ f16 As[128 * 40];
    __shared__ f16 Ws[128 * 40];

    f32x4 acc[4][4] = {};

    for (int kk = 0; kk < D_; kk += 32) {
        __syncthreads();
        {
            int r = tid >> 3;
            int c = (tid & 7) * 4;
            #pragma unroll
            for (int p = 0; p < 4; ++p) {
                int row = p * 32 + r;
                float4 va = *(const float4*)&X[(size_t)(m0 + row) * D_ + kk + c];
                f16x4 ha = { (f16)(va.x * qs), (f16)(va.y * qs), (f16)(va.z * qs), (f16)(va.w * qs) };
                *(f16x4*)&As[row * 40 + c] = ha;
                float4 vb = *(const float4*)&W[(size_t)(n0 + row) * D_ + kk + c];
                f16x4 hb = { (f16)vb.x, (f16)vb.y, (f16)vb.z, (f16)vb.w };
                *(f16x4*)&Ws[row * 40 + c] = hb;
            }
        }
        __syncthreads();

        f16x8 af[4], bf[4];
        const int lg = (lane >> 4) * 8;
        #pragma unroll
        for (int i = 0; i < 4; ++i) {
            af[i] = *(const f16x8*)&As[(wr + i * 16 + (lane & 15)) * 40 + lg];
            bf[i] = *(const f16x8*)&Ws[(wc + i * 16 + (lane & 15)) * 40 + lg];
        }
        #pragma unroll
        for (int i = 0; i < 4; ++i)
            #pragma unroll
            for (int j = 0; j < 4; ++j)
                acc[i][j] = __builtin_amdgcn_mfma_f32_16x16x32_f16(af[i], bf[j], acc[i][j], 0, 0, 0);
    }

    if (z == 2) {
        // V^T epilogue: reg index r = 4 consecutive l at fixed dv -> f16x4.
        #pragma unroll
        for (int i = 0; i < 4; ++i) {
            int grow = m0 + wr + i * 16 + (lane >> 4) * 4;
            int b = grow >> 11, l = grow & (L_ - 1);
            #pragma unroll
            for (int j = 0; j < 4; ++j) {
                int gcol = n0 + wc + j * 16 + (lane & 15);
                int hh = gcol >> 6, k = gcol & 63;
                f16x4 o = { (f16)acc[i][j][0], (f16)acc[i][j][1],
                            (f16)acc[i][j][2], (f16)acc[i][j][3] };
                *(f16x4*)&out[((size_t)((b * H_ + hh) * DK_ + k)) * L_ + l] = o;
            }
        }
    } else {
        #pragma unroll
        for (int i = 0; i < 4; ++i) {
            int grow = m0 + wr + i * 16 + (lane >> 4) * 4;
            #pragma unroll
            for (int j = 0; j < 4; ++j) {
                int gcol = n0 + wc + j * 16 + (lane & 15);
                int hh = gcol >> 6, k = gcol & 63;
                #pragma unroll
                for (int r = 0; r < 4; ++r) {
                    int row = grow + r;
                    int b = row >> 11, l = row & (L_ - 1);
                    out[(((size_t)(b * H_ + hh)) * L_ + l) * DK_ + k] = (f16)acc[i][j][r];
                }
            }
        }
    }
}

// ---------------------------------------------------------------------------
// Flash attention, swapped-operand form. Block = 4 waves, 64 q rows.
// S^T = mfma(K, Q): lane holds q = lane&15 -> per-lane scalar softmax.
// PV computes O^T = mfma(V^T, P^T). V^T comes pre-transposed from global.
// Mask offsets for all L keys staged once in LDS, folded into MFMA C-in.
// ---------------------------------------------------------------------------
__global__ __launch_bounds__(256) void attn_kernel(
    const f16* __restrict__ Qh, const f16* __restrict__ Kh,
    const f16* __restrict__ VhT, const int* __restrict__ mask,
    f16* __restrict__ Oh)
{
    // XCD swizzle: all 32 q-blocks of a (b,h) land on the same XCD (id%8).
    const int n = blockIdx.x;
    const int bh = ((n >> 8) << 3) + (n & 7);   // b*H + h
    const int qb = (n >> 3) & 31;
    const int b = bh >> 4, h = bh & 15;
    const int q0 = qb * 64;
    const int tid = threadIdx.x;
    const int lane = tid & 63;
    const int w = tid >> 6;
    const int lq = lane & 15, g = lane >> 4;

    __shared__ f16 Ks[64 * 72];
    __shared__ f16 Vt[64 * 72];
    __shared__ f16 Plds[4][16 * 72];
    __shared__ float moff[L_];

    const size_t base = (size_t)bh * L_ * DK_;

    // one-time: mask -> additive offsets for ALL keys (visible after 1st barrier)
    {
        const int4* mp = (const int4*)(mask + b * L_);
        #pragma unroll
        for (int t = 0; t < 2; ++t) {
            int4 mv = mp[tid * 2 + t];
            float4 f = { mv.x ? 0.f : MASKOFF, mv.y ? 0.f : MASKOFF,
                         mv.z ? 0.f : MASKOFF, mv.w ? 0.f : MASKOFF };
            *(float4*)&moff[tid * 8 + t * 4] = f;
        }
    }

    // Q fragment (B-operand): q = q0 + w*16 + lq, d = g*8 + j
    f16x8 qf[2];
    {
        int qrow = q0 + w * 16 + lq;
        const f16* qptr = Qh + base + (size_t)qrow * DK_ + g * 8;
        qf[0] = *(const f16x8*)(qptr);
        qf[1] = *(const f16x8*)(qptr + 32);
    }

    const int srow = tid >> 2, scol = (tid & 3) * 16;   // staging map (K and V^T)

    f32x4 acc[4] = {};   // O^T: dv = f*16 + g*4 + reg, q = lq
    float mrun = -1e30f, lrun = 0.f;

    f16x8 kA0, kA1, vA0, vA1;
    f16x8 kB0, kB1, vB0, vB1;

    auto issue = [&](int k0, f16x8& k0r, f16x8& k1r, f16x8& v0r, f16x8& v1r) {
        const f16* kp = Kh + base + (size_t)(k0 + srow) * DK_ + scol;
        k0r = *(const f16x8*)kp;
        k1r = *(const f16x8*)(kp + 8);
        const f16* vp = VhT + (size_t)(bh * DK_ + srow) * L_ + k0 + scol;
        v0r = *(const f16x8*)vp;
        v1r = *(const f16x8*)(vp + 8);
    };

    auto store_tile = [&](const f16x8& k0r, const f16x8& k1r,
                          const f16x8& v0r, const f16x8& v1r) {
        *(f16x8*)&Ks[srow * 72 + scol] = k0r;
        *(f16x8*)&Ks[srow * 72 + scol + 8] = k1r;
        *(f16x8*)&Vt[srow * 72 + scol] = v0r;
        *(f16x8*)&Vt[srow * 72 + scol + 8] = v1r;
    };

    auto compute = [&](int k0) {
        float sv[16];
        __builtin_amdgcn_s_setprio(1);
        #pragma unroll
        for (int kt = 0; kt < 4; ++kt) {
            f32x4 s = *(const f32x4*)&moff[k0 + kt * 16 + g * 4];  // mask as C-in
            const f16* ka = &Ks[(kt * 16 + lq) * 72 + g * 8];
            s = __builtin_amdgcn_mfma_f32_16x16x32_f16(*(const f16x8*)ka, qf[0], s, 0, 0, 0);
            s = __builtin_amdgcn_mfma_f32_16x16x32_f16(*(const f16x8*)(ka + 32), qf[1], s, 0, 0, 0);
            *(f32x4*)&sv[kt * 4] = s;
        }
        __builtin_amdgcn_s_setprio(0);

        // per-lane scalar max (row = this lane's q), 2 cross-group shuffles
        float a0 = fmaxf(sv[0], sv[1]),  a1 = fmaxf(sv[2], sv[3]);
        float a2 = fmaxf(sv[4], sv[5]),  a3 = fmaxf(sv[6], sv[7]);
        float a4 = fmaxf(sv[8], sv[9]),  a5 = fmaxf(sv[10], sv[11]);
        float a6 = fmaxf(sv[12], sv[13]), a7 = fmaxf(sv[14], sv[15]);
        float m = fmaxf(fmaxf(fmaxf(a0, a1), fmaxf(a2, a3)),
                        fmaxf(fmaxf(a4, a5), fmaxf(a6, a7)));
        m = fmaxf(m, __shfl_xor(m, 16, 64));
        m = fmaxf(m, __shfl_xor(m, 32, 64));

        // exact defer-max: rescale only when some lane's max actually grew
        if (__any(m > mrun)) {
            float mn = fmaxf(mrun, m);
            float scl = exp2f(mrun - mn);
            mrun = mn;
            lrun *= scl;
            #pragma unroll
            for (int f = 0; f < 4; ++f) acc[f] *= scl;
        }

        // P = exp2(s - mrun), pack to f16 (RTZ), vectorized LDS store
        f16* pl = (f16*)Plds[w];
        float ls0 = 0.f, ls1 = 0.f;
        #pragma unroll
        for (int kt = 0; kt < 4; ++kt) {
            float p0 = exp2f(sv[kt * 4 + 0] - mrun);
            float p1 = exp2f(sv[kt * 4 + 1] - mrun);
            float p2 = exp2f(sv[kt * 4 + 2] - mrun);
            float p3 = exp2f(sv[kt * 4 + 3] - mrun);
            ls0 += p0 + p1;
            ls1 += p2 + p3;
            hf16x2 lo = __builtin_amdgcn_cvt_pkrtz(p0, p1);
            hf16x2 hi = __builtin_amdgcn_cvt_pkrtz(p2, p3);
            f16x2 lo2 = __builtin_bit_cast(f16x2, lo);
            f16x2 hi2 = __builtin_bit_cast(f16x2, hi);
            f16x4 pk; pk[0] = lo2[0]; pk[1] = lo2[1]; pk[2] = hi2[0]; pk[3] = hi2[1];
            *(f16x4*)&pl[lq * 72 + kt * 16 + g * 4] = pk;
        }
        float ls = ls0 + ls1;
        ls += __shfl_xor(ls, 16, 64);
        ls += __shfl_xor(ls, 32, 64);
        lrun += ls;
        asm volatile("s_waitcnt lgkmcnt(0)" ::: "memory");  // P-store -> PV-read RAW

        // PV: O^T = V^T * P^T
        __builtin_amdgcn_s_setprio(1);
        #pragma unroll
        for (int kc = 0; kc < 2; ++kc) {
            f16x8 pb = *(const f16x8*)&pl[lq * 72 + kc * 32 + g * 8];
            #pragma unroll
            for (int f = 0; f < 4; ++f) {
                f16x8 va = *(const f16x8*)&Vt[(f * 16 + lq) * 72 + kc * 32 + g * 8];
                acc[f] = __builtin_amdgcn_mfma_f32_16x16x32_f16(va, pb, acc[f], 0, 0, 0);
            }
        }
        __builtin_amdgcn_s_setprio(0);
    };

    issue(0, kA0, kA1, vA0, vA1);
    for (int k0 = 0; k0 < L_; k0 += 128) {
        __syncthreads();
        store_tile(kA0, kA1, vA0, vA1);
        issue(k0 + 64, kB0, kB1, vB0, vB1);
        __syncthreads();
        compute(k0);

        __syncthreads();
        store_tile(kB0, kB1, vB0, vB1);
        if (k0 + 128 < L_) issue(k0 + 128, kA0, kA1, vA0, vA1);
        __syncthreads();
        compute(k0 + 64);
    }

    // epilogue: normalize (per-lane scalar l) and store O[q][dv] as f16x4
    float inv = 1.f / lrun;
    int q = q0 + w * 16 + lq;
    #pragma unroll
    for (int f = 0; f < 4; ++f) {
        f16x4 o = { (f16)(acc[f][0] * inv), (f16)(acc[f][1] * inv),
                    (f16)(acc[f][2] * inv), (f16)(acc[f][3] * inv) };
        *(f16x4*)&Oh[((size_t)(b * L_ + q)) * D_ + h * 64 + f * 16 + g * 4] = o;
    }
}

// ---------------------------------------------------------------------------
// Output projection GEMM (+bias), f32 out.
// ---------------------------------------------------------------------------
__global__ __launch_bounds__(256) void out_proj_kernel(
    const f16* __restrict__ Oh, const float* __restrict__ outw,
    const float* __restrict__ outb, float* __restrict__ Y)
{
    const int m0 = blockIdx.x * 128;
    const int n0 = blockIdx.y * 128;
    const int tid = threadIdx.x;
    const int lane = tid & 63;
    const int w = tid >> 6;
    const int wr = (w >> 1) * 64, wc = (w & 1) * 64;

    __shared__ f16 As[128 * 40];
    __shared__ f16 Ws[128 * 40];

    f32x4 acc[4][4] = {};

    for (int kk = 0; kk < D_; kk += 32) {
        __syncthreads();
        {
            int r = tid >> 3;
            int c = (tid & 7) * 4;
            #pragma unroll
            for (int p = 0; p < 4; ++p) {
                int row = p * 32 + r;
                f16x4 ha = *(const f16x4*)&Oh[(size_t)(m0 + row) * D_ + kk + c];
                *(f16x4*)&As[row * 40 + c] = ha;
                float4 vb = *(const float4*)&outw[(size_t)(n0 + row) * D_ + kk + c];
                f16x4 hb = { (f16)vb.x, (f16)vb.y, (f16)vb.z, (f16)vb.w };
                *(f16x4*)&Ws[row * 40 + c] = hb;
            }
        }
        __syncthreads();

        f16x8 af[4], bf[4];
        const int lg = (lane >> 4) * 8;
        #pragma unroll
        for (int i = 0; i < 4; ++i) {
            af[i] = *(const f16x8*)&As[(wr + i * 16 + (lane & 15)) * 40 + lg];
            bf[i] = *(const f16x8*)&Ws[(wc + i * 16 + (lane & 15)) * 40 + lg];
        }
        #pragma unroll
        for (int i = 0; i < 4; ++i)
            #pragma unroll
            for (int j = 0; j < 4; ++j)
                acc[i][j] = __builtin_amdgcn_mfma_f32_16x16x32_f16(af[i], bf[j], acc[i][j], 0, 0, 0);
    }

    #pragma unroll
    for (int i = 0; i < 4; ++i) {
        int grow = m0 + wr + i * 16 + (lane >> 4) * 4;
        #pragma unroll
        for (int j = 0; j < 4; ++j) {
            int gcol = n0 + wc + j * 16 + (lane & 15);
            float bias = outb[gcol];
            #pragma unroll
            for (int r = 0; r < 4; ++r)
                Y[(size_t)(grow + r) * D_ + gcol] = acc[i][j][r] + bias;
        }
    }
}

extern "C" void kernel_launch(void* const* d_in, const int* in_sizes, int n_in,
                              void* d_out, int out_size, void* d_ws, size_t ws_size,
                              hipStream_t stream) {
    const float* query = (const float*)d_in[0];
    const float* key   = (const float*)d_in[1];
    const float* value = (const float*)d_in[2];
    const float* Wq    = (const float*)d_in[3];
    const float* Wk    = (const float*)d_in[4];
    const float* Wv    = (const float*)d_in[5];
    const float* outw  = (const float*)d_in[7];
    const float* outb  = (const float*)d_in[8];
    const int*   mask  = (const int*)d_in[10];
    float* Y = (float*)d_out;

    char* ws = (char*)d_ws;
    f16* Qh  = (f16*)(ws);                 //  8 MiB: [b,h,l,k] f16 (pre-scaled)
    f16* Kh  = (f16*)(ws + 8388608);       //  8 MiB: [b,h,l,k]
    f16* VhT = (f16*)(ws + 16777216);      //  8 MiB: [b,h,k,l]  (V transposed)
    f16* Oh  = (f16*)(ws + 25165824);      //  8 MiB: [b,l,h*64+k]

    qkv_proj_kernel<<<dim3(32, 8, 3), 256, 0, stream>>>(query, key, value,
                                                        Wq, Wk, Wv, Qh, Kh, VhT);
    attn_kernel<<<dim3(1024), 256, 0, stream>>>(Qh, Kh, VhT, mask, Oh);
    out_proj_kernel<<<dim3(32, 8), 256, 0, stream>>>(Oh, outw, outb, Y);
}